// Round 21
// baseline (91.827 us; speedup 1.0000x reference)
//
#include <hip/hip_runtime.h>

typedef __attribute__((ext_vector_type(8))) short short8;
typedef __attribute__((ext_vector_type(4))) float f32x4;
typedef __attribute__((ext_vector_type(16))) float f32x16;
typedef __attribute__((ext_vector_type(2))) unsigned uint2v;
typedef __attribute__((ext_vector_type(4))) unsigned uint4v;

#define MFMA16(a,b,c) __builtin_amdgcn_mfma_f32_16x16x32_bf16((a),(b),(c),0,0,0)
#define MFMA32(a,b,c) __builtin_amdgcn_mfma_f32_32x32x16_bf16((a),(b),(c),0,0,0)

#define BB 32
#define SS 1024
#define DD 192
#define HH 8
#define DHP 32   // padded head dim (24 -> 32); col 31 = mask-bias, col 24 of V = ones

// Q pre-scale: log2(e) / sqrt(24)  -> exp2(S) == softmax numerator
#define SCALE_Q 0.294468266742895f

__device__ __forceinline__ short nb(float f) {
    __bf16 h = (__bf16)f;
    return __builtin_bit_cast(short, h);
}
__device__ __forceinline__ unsigned pk2(float a, float b) {
    unsigned short lo = __builtin_bit_cast(unsigned short, (__bf16)a);
    unsigned short hi = __builtin_bit_cast(unsigned short, (__bf16)b);
    return (unsigned)lo | ((unsigned)hi << 16);
}

// ---------------- setup: weights-frag + x-frag + mask scan, fused ----------------
// blocks [0,720): weight layouts; [720,1232): xprep; [1232,1264): scan
#define NBLK_PREP 720
#define NBLK_XPREP 512
__global__ __launch_bounds__(256) void setup_kernel(
    const float* __restrict__ Wq, const float* __restrict__ Wk, const float* __restrict__ Wv,
    const float* __restrict__ Wo, const float* __restrict__ x, const void* __restrict__ mask_raw,
    short* __restrict__ WqF, short* __restrict__ WkF, short* __restrict__ WvF,
    short* __restrict__ WoFh, short* __restrict__ xF,
    float* __restrict__ maskf, int* __restrict__ fwd, int* __restrict__ cnt)
{
    __shared__ short lds[64][200];   // xprep staging; scan aliases first 16 B
    int bid = blockIdx.x;
    int t = threadIdx.x;

    if (bid < NBLK_PREP) {
        int idx = bid * 256 + t;
        const int NWX = 3 * HH * DHP * DD;     // 147456
        const int NWO = DD * DD;               // 36864
        if (idx < NWX) {
            int mat = idx / (HH * DHP * DD);
            int jj  = idx % (HH * DHP * DD);
            int h   = jj / (DHP * DD);
            int rem = jj % (DHP * DD);
            int e   = rem / DD;
            int d   = rem % DD;
            const float* W = (mat == 0) ? Wq : (mat == 1) ? Wk : Wv;
            short* WF      = (mat == 0) ? WqF : (mat == 1) ? WkF : WvF;
            float val = (e < 24) ? W[(h * DD + d) * 24 + e] : 0.f;
            int nt = e & 1, cc = e >> 1;
            int kk = d >> 5, g = (d >> 3) & 3, ee = d & 7;
            WF[(size_t)((((h*2+nt)*6 + kk)*64) + g*16 + cc)*8 + ee] = nb(val);
        } else if (idx < NWX + NWO) {
            int j = idx - NWX;
            int n = j / DD, k = j % DD;
            int nn = n >> 4, cc = n & 15;
            int kk = k >> 5, g = (k >> 3) & 3, ee = k & 7;
            WoFh[(size_t)(((nn*6 + kk)*64) + g*16 + cc)*8 + ee] = nb(Wo[k * DD + n]);
        }
    } else if (bid < NBLK_PREP + NBLK_XPREP) {
        // ---- xprep: x (f32) -> xF bf16 A-fragment order ----
        int xb = bid - NBLK_PREP;
        int r0 = xb * 64;
        #pragma unroll
        for (int i = 0; i < 12; i++) {
            int idx = i * 256 + t;
            int row = idx / 48;
            int colf = (idx % 48) * 4;
            float4 f = *(const float4*)(x + ((size_t)(r0 + row)) * DD + colf);
            lds[row][colf + 0] = nb(f.x);
            lds[row][colf + 1] = nb(f.y);
            lds[row][colf + 2] = nb(f.z);
            lds[row][colf + 3] = nb(f.w);
        }
        __syncthreads();
        int w = t >> 6, lane = t & 63, c = lane & 15, g = lane >> 4;
        short* outb = xF + (size_t)(xb * 4 + w) * 6 * 512;
        #pragma unroll
        for (int kk = 0; kk < 6; kk++) {
            short8 o = *(const short8*)&lds[w * 16 + c][kk * 32 + g * 8];
            *(short8*)(outb + kk * 512 + (size_t)lane * 8) = o;
        }
    } else {
        // ---- scan: mask normalize + per-batch stable compaction (fwd) ----
        int b = bid - NBLK_PREP - NBLK_XPREP;
        int lane = t & 63, wv = t >> 6;
        int* wsu = (int*)&lds[0][0];

        const unsigned* mw = (const unsigned*)mask_raw;
        bool all01 = true, allf = true;
        #pragma unroll
        for (int i = 0; i < 16; i++) {
            unsigned w = mw[i];
            all01 = all01 && (w <= 1u);
            allf  = allf  && (w == 0u || w == 0x3F800000u);
        }
        int s0 = t * 4;
        bool m[4];
        #pragma unroll
        for (int j = 0; j < 4; j++) {
            int idx = b * SS + s0 + j;
            bool mm;
            if (all01)      mm = (mw[idx] != 0u);
            else if (allf)  mm = (((const float*)mask_raw)[idx] != 0.f);
            else            mm = (((const unsigned char*)mask_raw)[idx] != 0);
            m[j] = mm;
            maskf[idx] = mm ? 1.f : 0.f;
        }
        int cnt4 = (int)m[0] + (int)m[1] + (int)m[2] + (int)m[3];
        int pref = cnt4;
        #pragma unroll
        for (int d = 1; d < 64; d <<= 1) {
            int o = __shfl_up(pref, d, 64);
            if (lane >= d) pref += o;
        }
        int waveExcl = pref - cnt4;
        if (lane == 63) wsu[wv] = pref;   // wave total
        __syncthreads();
        int waveOff = 0, totalU = 0;
        #pragma unroll
        for (int i = 0; i < 4; i++) {
            int v = wsu[i];
            if (i < wv) waveOff += v;
            totalU += v;
        }
        int pu = waveOff + waveExcl;
        #pragma unroll
        for (int j = 0; j < 4; j++) {
            int s = s0 + j;
            if (m[j]) { fwd[b * SS + pu] = s; pu++; }
            else      { fwd[b * SS + totalU + (s - pu)] = s; }
        }
        if (t == 0) cnt[b] = totalU;
    }
}

// ---------------- projq: Q = xF @ Wq + bq (LDS-free, high occupancy) ----------------
// grid 2048 = 512 row-blocks x 4 head-pairs. Q[:,31]=1, pre-scaled by SCALE_Q.
__global__ __launch_bounds__(256) void projq_kernel(
    const short* __restrict__ xF, const float* __restrict__ bq,
    const short* __restrict__ WqF, short* __restrict__ Q)
{
    int bid = blockIdx.x;
    int t = threadIdx.x;
    int lane = t & 63, w = t >> 6;
    int c = lane & 15, g = lane >> 4;

    int rb = bid & 511, hp = bid >> 9;
    int r0 = rb * 64 + w * 16;
    int b_ = r0 >> 10;
    int s0 = (r0 & 1023) + g * 4;

    short8 a[6];
    const short* xfb = xF + (size_t)(r0 >> 4) * 6 * 512 + (size_t)lane * 8;
    #pragma unroll
    for (int kk = 0; kk < 6; kk++)
        a[kk] = *(const short8*)(xfb + kk * 512);

    #pragma unroll
    for (int hh = 0; hh < 2; hh++) {
        int h = hp * 2 + hh;
        int bh = b_ * HH + h;
        f32x4 acc0 = {0.f,0.f,0.f,0.f};
        f32x4 acc1 = {0.f,0.f,0.f,0.f};
        const short* Wp0 = WqF + (size_t)((h*2+0)*6) * 512 + lane * 8;
        const short* Wp1 = WqF + (size_t)((h*2+1)*6) * 512 + lane * 8;
        #pragma unroll
        for (int kk = 0; kk < 6; kk++) {
            short8 b0 = *(const short8*)(Wp0 + kk * 512);
            short8 b1 = *(const short8*)(Wp1 + kk * 512);
            acc0 = MFMA16(a[kk], b0, acc0);
            acc1 = MFMA16(a[kk], b1, acc1);
        }
        float bv0 = 0.f, bv1 = 0.f;
        if (2*c < 24) {
            float2 bb = *(const float2*)(bq + h * 24 + 2 * c);
            bv0 = bb.x; bv1 = bb.y;
        }
        #pragma unroll
        for (int r = 0; r < 4; r++) {
            float v0 = (acc0[r] + bv0) * SCALE_Q;
            float v1 = (c == 15) ? 1.0f : (acc1[r] + bv1) * SCALE_Q;
            *(unsigned*)(Q + ((size_t)bh * SS + s0 + r) * DHP + 2*c) = pk2(v0, v1);
        }
    }
}

// ---------------- projkv: gather compacted x rows, K/V MFMA, emit KF/VF ----------------
// grid 2048 = (b, head-pair, 64-row chunk); skips chunks >= nt32.
// KF element (kpos,e): tile=kpos>>5, instr=e>>4, lane=((e>>3)&1)*32+(kpos&31), j=e&7
// VF element (kpos,e): tile=kpos>>5, instr=(kpos>>4)&1, lane=((kpos>>3)&1)*32+e, j=kpos&7
__global__ __launch_bounds__(256) void projkv_kernel(
    const float* __restrict__ x,
    const float* __restrict__ bk, const float* __restrict__ bv,
    const short* __restrict__ WkF, const short* __restrict__ WvF,
    const float* __restrict__ maskf, const int* __restrict__ fwd, const int* __restrict__ cnt,
    short* __restrict__ KF, short* __restrict__ VF)
{
    __shared__ short lds[64][200];   // gather buffer; klds/vlds alias it after A-frag reads
    __shared__ int   srows[64];

    int kb = blockIdx.x;
    int t = threadIdx.x;
    int lane = t & 63, w = t >> 6;
    int c = lane & 15, g = lane >> 4;

    int chunk = kb & 15, hp = (kb >> 4) & 3, b = kb >> 6;
    int row0 = chunk * 64;
    int nt32 = ((cnt[b] + 31) >> 5) << 5;
    if (row0 >= nt32) return;

    // gather 64 compacted rows of x (f32 -> bf16 in LDS), 4 lanes per row
    {
        int j = t >> 2, part = t & 3;
        int s = fwd[b * SS + row0 + j];
        if (part == 0) srows[j] = s;
        const float* xr = x + ((size_t)(b * SS + s)) * DD + part * 48;
        #pragma unroll
        for (int i = 0; i < 12; i++) {
            float4 f = *(const float4*)(xr + i * 4);
            int col = part * 48 + i * 4;
            *(unsigned*)&lds[j][col]     = pk2(f.x, f.y);
            *(unsigned*)&lds[j][col + 2] = pk2(f.z, f.w);
        }
    }
    __syncthreads();

    // A-fragments: wave w owns rows w*16..w*16+15
    short8 a[6];
    #pragma unroll
    for (int kk = 0; kk < 6; kk++)
        a[kk] = *(const short8*)&lds[w * 16 + c][kk * 32 + g * 8];

    float mrow[4];
    #pragma unroll
    for (int r = 0; r < 4; r++)
        mrow[r] = maskf[b * SS + srows[w * 16 + g * 4 + r]];

    // emit staging buffers alias the (now dead) gather buffer
    short (*klds)[40] = (short(*)[40])&lds[0][0];
    short (*vlds)[40] = (short(*)[40])(&lds[0][0] + 64 * 40);

    #pragma unroll
    for (int hh = 0; hh < 2; hh++) {
        int h = hp * 2 + hh;
        int bh = b * HH + h;

        f32x4 aK0 = {0.f,0.f,0.f,0.f}, aK1 = {0.f,0.f,0.f,0.f};
        f32x4 aV0 = {0.f,0.f,0.f,0.f}, aV1 = {0.f,0.f,0.f,0.f};
        const short* Kp0 = WkF + (size_t)((h*2+0)*6) * 512 + lane * 8;
        const short* Kp1 = WkF + (size_t)((h*2+1)*6) * 512 + lane * 8;
        const short* Vp0 = WvF + (size_t)((h*2+0)*6) * 512 + lane * 8;
        const short* Vp1 = WvF + (size_t)((h*2+1)*6) * 512 + lane * 8;
        #pragma unroll
        for (int kk = 0; kk < 6; kk++) {
            aK0 = MFMA16(a[kk], *(const short8*)(Kp0 + kk * 512), aK0);
            aK1 = MFMA16(a[kk], *(const short8*)(Kp1 + kk * 512), aK1);
            aV0 = MFMA16(a[kk], *(const short8*)(Vp0 + kk * 512), aV0);
            aV1 = MFMA16(a[kk], *(const short8*)(Vp1 + kk * 512), aV1);
        }
        float bk0 = 0.f, bk1 = 0.f, bvv0 = 0.f, bvv1 = 0.f;
        if (2*c < 24) {
            float2 kb2 = *(const float2*)(bk + h * 24 + 2 * c);
            float2 vb2 = *(const float2*)(bv + h * 24 + 2 * c);
            bk0 = kb2.x; bk1 = kb2.y; bvv0 = vb2.x; bvv1 = vb2.y;
        }

        // guard: hh=0 -> A-frag reads done; hh=1 -> prev emit reads done
        __syncthreads();
        #pragma unroll
        for (int r = 0; r < 4; r++) {
            int row = w * 16 + g * 4 + r;
            float k0v = aK0[r] + bk0;
            float k1v = (c == 15) ? ((mrow[r] != 0.f) ? 0.f : -1e30f) : (aK1[r] + bk1);
            *(unsigned*)&klds[row][2 * c] = pk2(k0v, k1v);
            float v0v = (c == 12) ? 1.0f : (aV0[r] + bvv0);   // col 24 = ones
            float v1v = aV1[r] + bvv1;
            *(unsigned*)&vlds[row][2 * c] = pk2(v0v, v1v);
        }
        __syncthreads();
        if (t < 128) {   // K emit: 2 tiles
            int tt = (t >> 6) & 1, L = t & 63, l3 = L & 31, h2 = L >> 5;
            short* kf0 = KF + (size_t)bh * SS * DHP + (size_t)(row0 / 32 + tt) * 1024;
            #pragma unroll
            for (int i = 0; i < 2; i++) {
                short8 o = *(const short8*)&klds[tt * 32 + l3][i * 16 + h2 * 8];
                *(short8*)(kf0 + i * 512 + (size_t)L * 8) = o;
            }
        } else {         // V emit: 2 tiles, transposed
            int t2 = t - 128;
            int tt = (t2 >> 6) & 1, L = t2 & 63, l3 = L & 31, h2 = L >> 5;
            short* vf0 = VF + (size_t)bh * SS * DHP + (size_t)(row0 / 32 + tt) * 1024;
            #pragma unroll
            for (int i = 0; i < 2; i++) {
                short8 o;
                #pragma unroll
                for (int j2 = 0; j2 < 8; j2++)
                    o[j2] = vlds[tt * 32 + i * 16 + h2 * 8 + j2][l3];
                *(short8*)(vf0 + i * 512 + (size_t)L * 8) = o;
            }
        }
    }
}

// ---------------- flash attention (swapped QK^T, in-register softmax) ----------------
__device__ __forceinline__ void fproc(const f32x16& S, f32x16& acc,
                                      short8 v0, short8 v1)
{
    float p[16];
    #pragma unroll
    for (int r = 0; r < 16; r++) p[r] = __builtin_amdgcn_exp2f(S[r]);

    unsigned c01 = pk2(p[0],  p[1]);
    unsigned c23 = pk2(p[2],  p[3]);
    unsigned c45 = pk2(p[4],  p[5]);
    unsigned c67 = pk2(p[6],  p[7]);
    unsigned c89 = pk2(p[8],  p[9]);
    unsigned cab = pk2(p[10], p[11]);
    unsigned ccd = pk2(p[12], p[13]);
    unsigned cef = pk2(p[14], p[15]);

    uint2v s0 = __builtin_amdgcn_permlane32_swap(c01, c45, false, false);
    uint2v s1 = __builtin_amdgcn_permlane32_swap(c23, c67, false, false);
    uint2v s2 = __builtin_amdgcn_permlane32_swap(c89, ccd, false, false);
    uint2v s3 = __builtin_amdgcn_permlane32_swap(cab, cef, false, false);

    uint4v w0v = { s0.x, s1.x, s0.y, s1.y };   // PV A-frag, kpos tile 0..15
    uint4v w1v = { s2.x, s3.x, s2.y, s3.y };   // kpos tile 16..31
    short8 pa0 = __builtin_bit_cast(short8, w0v);
    short8 pa1 = __builtin_bit_cast(short8, w1v);

    acc = MFMA32(pa0, v0, acc);
    acc = MFMA32(pa1, v1, acc);
}

// grid 512 = 256 bh x 2 qb; 4 q-chunks per wave (ILP-4 per K/V load)
__global__ __launch_bounds__(256, 2) void flash_kernel(
    const short* __restrict__ Q, const short* __restrict__ KF, const short* __restrict__ VF,
    const int* __restrict__ cnt, short* __restrict__ Af)
{
    __shared__ float llds[4][4][32];

    int idx = blockIdx.x;
    int bh = idx & 255;
    int qb = idx >> 8;          // 0..1
    int b = bh >> 3, h = bh & 7;

    int tid = threadIdx.x;
    int lane = tid & 63, w = tid >> 6;
    int l31 = lane & 31;
    int hi = lane >> 5;

    int nt = (cnt[b] + 31) >> 5;

    int qr0 = qb * 512 + w * 32;   // chunks at qr0 + cc*128

    short8 qf[4][2];
    #pragma unroll
    for (int cc = 0; cc < 4; cc++) {
        const short* Qp = Q + ((size_t)bh * SS + qr0 + cc * 128 + l31) * DHP + hi * 8;
        qf[cc][0] = *(const short8*)Qp;
        qf[cc][1] = *(const short8*)(Qp + 16);
    }

    const short* Kp = KF + (size_t)bh * SS * DHP + (size_t)lane * 8;
    const short* Vp = VF + (size_t)bh * SS * DHP + (size_t)lane * 8;

    f32x16 acc[4], Z16;
    #pragma unroll
    for (int r = 0; r < 16; r++) {
        acc[0][r] = 0.f; acc[1][r] = 0.f; acc[2][r] = 0.f; acc[3][r] = 0.f;
        Z16[r] = 0.f;
    }

    short8 k0 = *(const short8*)(Kp);
    short8 k1 = *(const short8*)(Kp + 512);
    short8 v0 = *(const short8*)(Vp);
    short8 v1 = *(const short8*)(Vp + 512);

    for (int kt = 0; kt < nt; kt++) {
        Kp += 1024;
        Vp += 1024;
        short8 nk0 = *(const short8*)(Kp);
        short8 nk1 = *(const short8*)(Kp + 512);
        short8 nv0 = *(const short8*)(Vp);
        short8 nv1 = *(const short8*)(Vp + 512);

        #pragma unroll
        for (int cc = 0; cc < 4; cc++) {
            f32x16 S = MFMA32(k0, qf[cc][0], Z16);
            S = MFMA32(k1, qf[cc][1], S);   // includes mask bias via channel e=31
            fproc(S, acc[cc], v0, v1);
        }

        k0 = nk0; k1 = nk1; v0 = nv0; v1 = nv1;
    }

    if (l31 == 24) {
        #pragma unroll
        for (int cc = 0; cc < 4; cc++) {
            #pragma unroll
            for (int r = 0; r < 16; r++) {
                int row = (r & 3) + 8 * (r >> 2) + 4 * hi;
                llds[w][cc][row] = __builtin_amdgcn_rcpf(acc[cc][r]);
            }
        }
    }
    __builtin_amdgcn_wave_barrier();

    if (l31 < 24) {
        int d = h * 24 + l31;
        size_t fcol = (size_t)((d >> 5) * 4 + ((d >> 3) & 3)) * 128 + (d & 7);
        #pragma unroll
        for (int cc = 0; cc < 4; cc++) {
            int grp = (b * SS + qr0 + cc * 128) >> 4;
            short* op = Af + (size_t)grp * 3072 + fcol;   // 3072 = 24*128
            #pragma unroll
            for (int r = 0; r < 16; r++) {
                int row = (r & 3) + 8 * (r >> 2) + 4 * hi;
                size_t off = (size_t)(r >> 3) * 3072 + (size_t)(row & 15) * 8;
                op[off] = nb(acc[cc][r] * llds[w][cc][row]);
            }
        }
    }
}

// ---------------- final: out = attn(bf16) @ Wo(bf16) + bo ----------------
__global__ __launch_bounds__(256) void final_kernel(
    const short* __restrict__ Af,
    const short* __restrict__ WoFh,
    const float* __restrict__ bo, float* __restrict__ out)
{
    int tid = threadIdx.x;
    int lane = tid & 63, w = tid >> 6;
    int c = lane & 15, g = lane >> 4;
    int r0 = blockIdx.x * 64 + w * 16;
    int n0 = blockIdx.y * 3;

    short8 a[6];
    #pragma unroll
    for (int kk = 0; kk < 6; kk++)
        a[kk] = *(const short8*)(Af + ((size_t)(r0 >> 4) * 24 + kk*4 + g) * 128 + c * 8);

    f32x4 acc[3];
    #pragma unroll
    for (int n = 0; n < 3; n++) acc[n] = (f32x4){0.f,0.f,0.f,0.f};

    #pragma unroll
    for (int kk = 0; kk < 6; kk++) {
        #pragma unroll
        for (int n = 0; n < 3; n++) {
            short8 bh = *(const short8*)(WoFh + (size_t)((n0+n)*6 + kk) * 512 + lane * 8);
            acc[n] = MFMA16(a[kk], bh, acc[n]);
        }
    }

    #pragma unroll
    for (int n = 0; n < 3; n++) {
        int col = (n0+n)*16 + c;
        float bv = bo[col];
        #pragma unroll
        for (int r = 0; r < 4; r++) {
            out[(size_t)(r0 + g*4 + r) * DD + col] = acc[n][r] + bv;
        }
    }
}

extern "C" void kernel_launch(void* const* d_in, const int* in_sizes, int n_in,
                              void* d_out, int out_size, void* d_ws, size_t ws_size,
                              hipStream_t stream)
{
    const float* x    = (const float*)d_in[0];
    const void*  mask = d_in[1];
    const float* Wq   = (const float*)d_in[2];
    const float* bq   = (const float*)d_in[3];
    const float* Wk   = (const float*)d_in[4];
    const float* bk   = (const float*)d_in[5];
    const float* Wv   = (const float*)d_in[6];
    const float* bv   = (const float*)d_in[7];
    const float* Wo   = (const float*)d_in[8];
    const float* bo   = (const float*)d_in[9];
    float* out = (float*)d_out;

    char* ws = (char*)d_ws;
    size_t off = 0;
    float* maskf = (float*)(ws + off); off += (size_t)BB*SS*4;          // 128 KB
    short* Q     = (short*)(ws + off); off += (size_t)BB*HH*SS*DHP*2;   // 16 MB
    short* KF    = (short*)(ws + off); off += (size_t)BB*HH*SS*DHP*2;   // 16 MB
    short* VF    = (short*)(ws + off); off += (size_t)BB*HH*SS*DHP*2;   // 16 MB
    short* Af    = (short*)(ws + off); off += (size_t)BB*SS*DD*2;       // 12 MB
    short* xF    = (short*)(ws + off); off += (size_t)BB*SS*DD*2;       // 12.6 MB
    short* WqF   = (short*)(ws + off); off += (size_t)HH*DHP*DD*2;
    short* WkF   = (short*)(ws + off); off += (size_t)HH*DHP*DD*2;
    short* WvF   = (short*)(ws + off); off += (size_t)HH*DHP*DD*2;
    short* WoFh  = (short*)(ws + off); off += (size_t)DD*DD*2;
    int*   fwd   = (int*)  (ws + off); off += (size_t)BB*SS*4;          // 128 KB
    int*   cnt   = (int*)  (ws + off); off += 256;

    setup_kernel<<<dim3(NBLK_PREP + NBLK_XPREP + BB), dim3(256), 0, stream>>>(
        Wq, Wk, Wv, Wo, x, mask, WqF, WkF, WvF, WoFh, xF, maskf, fwd, cnt);
    projkv_kernel<<<dim3(2048), dim3(256), 0, stream>>>(
        x, bk, bv, WkF, WvF, maskf, fwd, cnt, KF, VF);
    projq_kernel<<<dim3(2048), dim3(256), 0, stream>>>(
        xF, bq, WqF, Q);
    flash_kernel<<<dim3(512), dim3(256), 0, stream>>>(
        Q, KF, VF, cnt, Af);
    final_kernel<<<dim3(512, 4), dim3(256), 0, stream>>>(
        Af, WoFh, bo, out);
}

// Round 22
// 88.724 us; speedup vs baseline: 1.0350x; 1.0350x over previous
//
#include <hip/hip_runtime.h>

typedef __attribute__((ext_vector_type(8))) short short8;
typedef __attribute__((ext_vector_type(4))) float f32x4;
typedef __attribute__((ext_vector_type(16))) float f32x16;
typedef __attribute__((ext_vector_type(2))) unsigned uint2v;
typedef __attribute__((ext_vector_type(4))) unsigned uint4v;

#define MFMA16(a,b,c) __builtin_amdgcn_mfma_f32_16x16x32_bf16((a),(b),(c),0,0,0)
#define MFMA32(a,b,c) __builtin_amdgcn_mfma_f32_32x32x16_bf16((a),(b),(c),0,0,0)

#define BB 32
#define SS 1024
#define DD 192
#define HH 8
#define DHP 32   // padded head dim (24 -> 32); col 31 = mask-bias, col 24 of V = ones

// Q pre-scale: log2(e) / sqrt(24)  -> exp2(S) == softmax numerator
#define SCALE_Q 0.294468266742895f

__device__ __forceinline__ short nb(float f) {
    __bf16 h = (__bf16)f;
    return __builtin_bit_cast(short, h);
}
__device__ __forceinline__ unsigned pk2(float a, float b) {
    unsigned short lo = __builtin_bit_cast(unsigned short, (__bf16)a);
    unsigned short hi = __builtin_bit_cast(unsigned short, (__bf16)b);
    return (unsigned)lo | ((unsigned)hi << 16);
}

// ---------------- setup: weights-frag + x-frag + mask scan, fused ----------------
// blocks [0,720): weight layouts; [720,1232): xprep; [1232,1264): scan
#define NBLK_PREP 720
#define NBLK_XPREP 512
__global__ __launch_bounds__(256) void setup_kernel(
    const float* __restrict__ Wq, const float* __restrict__ Wk, const float* __restrict__ Wv,
    const float* __restrict__ Wo, const float* __restrict__ x, const void* __restrict__ mask_raw,
    short* __restrict__ WqF, short* __restrict__ WkF, short* __restrict__ WvF,
    short* __restrict__ WoFh, short* __restrict__ xF,
    float* __restrict__ maskf, int* __restrict__ fwd, int* __restrict__ cnt)
{
    __shared__ short lds[64][200];   // xprep staging; scan aliases first 16 B
    int bid = blockIdx.x;
    int t = threadIdx.x;

    if (bid < NBLK_PREP) {
        int idx = bid * 256 + t;
        const int NWX = 3 * HH * DHP * DD;     // 147456
        const int NWO = DD * DD;               // 36864
        if (idx < NWX) {
            int mat = idx / (HH * DHP * DD);
            int jj  = idx % (HH * DHP * DD);
            int h   = jj / (DHP * DD);
            int rem = jj % (DHP * DD);
            int e   = rem / DD;
            int d   = rem % DD;
            const float* W = (mat == 0) ? Wq : (mat == 1) ? Wk : Wv;
            short* WF      = (mat == 0) ? WqF : (mat == 1) ? WkF : WvF;
            float val = (e < 24) ? W[(h * DD + d) * 24 + e] : 0.f;
            int nt = e & 1, cc = e >> 1;
            int kk = d >> 5, g = (d >> 3) & 3, ee = d & 7;
            WF[(size_t)((((h*2+nt)*6 + kk)*64) + g*16 + cc)*8 + ee] = nb(val);
        } else if (idx < NWX + NWO) {
            int j = idx - NWX;
            int n = j / DD, k = j % DD;
            int nn = n >> 4, cc = n & 15;
            int kk = k >> 5, g = (k >> 3) & 3, ee = k & 7;
            WoFh[(size_t)(((nn*6 + kk)*64) + g*16 + cc)*8 + ee] = nb(Wo[k * DD + n]);
        }
    } else if (bid < NBLK_PREP + NBLK_XPREP) {
        // ---- xprep: x (f32) -> xF bf16 A-fragment order ----
        int xb = bid - NBLK_PREP;
        int r0 = xb * 64;
        #pragma unroll
        for (int i = 0; i < 12; i++) {
            int idx = i * 256 + t;
            int row = idx / 48;
            int colf = (idx % 48) * 4;
            float4 f = *(const float4*)(x + ((size_t)(r0 + row)) * DD + colf);
            lds[row][colf + 0] = nb(f.x);
            lds[row][colf + 1] = nb(f.y);
            lds[row][colf + 2] = nb(f.z);
            lds[row][colf + 3] = nb(f.w);
        }
        __syncthreads();
        int w = t >> 6, lane = t & 63, c = lane & 15, g = lane >> 4;
        short* outb = xF + (size_t)(xb * 4 + w) * 6 * 512;
        #pragma unroll
        for (int kk = 0; kk < 6; kk++) {
            short8 o = *(const short8*)&lds[w * 16 + c][kk * 32 + g * 8];
            *(short8*)(outb + kk * 512 + (size_t)lane * 8) = o;
        }
    } else {
        // ---- scan: mask normalize + per-batch stable compaction (fwd) ----
        int b = bid - NBLK_PREP - NBLK_XPREP;
        int lane = t & 63, wv = t >> 6;
        int* wsu = (int*)&lds[0][0];

        const unsigned* mw = (const unsigned*)mask_raw;
        bool all01 = true, allf = true;
        #pragma unroll
        for (int i = 0; i < 16; i++) {
            unsigned w = mw[i];
            all01 = all01 && (w <= 1u);
            allf  = allf  && (w == 0u || w == 0x3F800000u);
        }
        int s0 = t * 4;
        bool m[4];
        #pragma unroll
        for (int j = 0; j < 4; j++) {
            int idx = b * SS + s0 + j;
            bool mm;
            if (all01)      mm = (mw[idx] != 0u);
            else if (allf)  mm = (((const float*)mask_raw)[idx] != 0.f);
            else            mm = (((const unsigned char*)mask_raw)[idx] != 0);
            m[j] = mm;
            maskf[idx] = mm ? 1.f : 0.f;
        }
        int cnt4 = (int)m[0] + (int)m[1] + (int)m[2] + (int)m[3];
        int pref = cnt4;
        #pragma unroll
        for (int d = 1; d < 64; d <<= 1) {
            int o = __shfl_up(pref, d, 64);
            if (lane >= d) pref += o;
        }
        int waveExcl = pref - cnt4;
        if (lane == 63) wsu[wv] = pref;   // wave total
        __syncthreads();
        int waveOff = 0, totalU = 0;
        #pragma unroll
        for (int i = 0; i < 4; i++) {
            int v = wsu[i];
            if (i < wv) waveOff += v;
            totalU += v;
        }
        int pu = waveOff + waveExcl;
        #pragma unroll
        for (int j = 0; j < 4; j++) {
            int s = s0 + j;
            if (m[j]) { fwd[b * SS + pu] = s; pu++; }
            else      { fwd[b * SS + totalU + (s - pu)] = s; }
        }
        if (t == 0) cnt[b] = totalU;
    }
}

// ---------------- proj2: projq [0,2048) + projkv [2048,4096) ----------------
// projq: Q = xF @ Wq (frag-ordered reads, 2 heads/block). Q[:,31]=1, pre-scaled.
// projkv: gather 64 compacted x rows into LDS (4 lanes/row, coalesced-ish),
//   K/V MFMA, emit KF/VF fragment-tiles. Emit buffers ALIAS the gather buffer
//   (dead after A-frag reads) -> 25.6 KB LDS total, 6 blocks/CU, 5 syncs.
// KF element (kpos,e): tile=kpos>>5, instr=e>>4, lane=((e>>3)&1)*32+(kpos&31), j=e&7
// VF element (kpos,e): tile=kpos>>5, instr=(kpos>>4)&1, lane=((kpos>>3)&1)*32+e, j=kpos&7
__global__ __launch_bounds__(256) void proj2_kernel(
    const float* __restrict__ x, const short* __restrict__ xF,
    const float* __restrict__ bq, const float* __restrict__ bk, const float* __restrict__ bv,
    const short* __restrict__ WqF, const short* __restrict__ WkF, const short* __restrict__ WvF,
    const float* __restrict__ maskf, const int* __restrict__ fwd, const int* __restrict__ cnt,
    short* __restrict__ Q, short* __restrict__ KF, short* __restrict__ VF)
{
    __shared__ short lds[64][200];   // gather buffer; klds/vlds alias it after A-frag reads
    __shared__ int   srows[64];

    int bid = blockIdx.x;
    int t = threadIdx.x;
    int lane = t & 63, w = t >> 6;
    int c = lane & 15, g = lane >> 4;

    if (bid < 2048) {
        // ---------------- projq ----------------
        int rb = bid & 511, hp = bid >> 9;
        int r0 = rb * 64 + w * 16;
        int b_ = r0 >> 10;
        int s0 = (r0 & 1023) + g * 4;

        short8 a[6];
        const short* xfb = xF + (size_t)(r0 >> 4) * 6 * 512 + (size_t)lane * 8;
        #pragma unroll
        for (int kk = 0; kk < 6; kk++)
            a[kk] = *(const short8*)(xfb + kk * 512);

        #pragma unroll
        for (int hh = 0; hh < 2; hh++) {
            int h = hp * 2 + hh;
            int bh = b_ * HH + h;
            f32x4 acc0 = {0.f,0.f,0.f,0.f};
            f32x4 acc1 = {0.f,0.f,0.f,0.f};
            const short* Wp0 = WqF + (size_t)((h*2+0)*6) * 512 + lane * 8;
            const short* Wp1 = WqF + (size_t)((h*2+1)*6) * 512 + lane * 8;
            #pragma unroll
            for (int kk = 0; kk < 6; kk++) {
                short8 b0 = *(const short8*)(Wp0 + kk * 512);
                short8 b1 = *(const short8*)(Wp1 + kk * 512);
                acc0 = MFMA16(a[kk], b0, acc0);
                acc1 = MFMA16(a[kk], b1, acc1);
            }
            float bv0 = 0.f, bv1 = 0.f;
            if (2*c < 24) {
                float2 bb = *(const float2*)(bq + h * 24 + 2 * c);
                bv0 = bb.x; bv1 = bb.y;
            }
            #pragma unroll
            for (int r = 0; r < 4; r++) {
                float v0 = (acc0[r] + bv0) * SCALE_Q;
                float v1 = (c == 15) ? 1.0f : (acc1[r] + bv1) * SCALE_Q;
                *(unsigned*)(Q + ((size_t)bh * SS + s0 + r) * DHP + 2*c) = pk2(v0, v1);
            }
        }
        return;
    }

    // ---------------- projkv ----------------
    int kb = bid - 2048;
    int chunk = kb & 15, hp = (kb >> 4) & 3, b = kb >> 6;
    int row0 = chunk * 64;
    int nt32 = ((cnt[b] + 31) >> 5) << 5;
    if (row0 >= nt32) return;

    // gather 64 compacted rows of x (f32 -> bf16 in LDS), 4 lanes per row
    {
        int j = t >> 2, part = t & 3;
        int s = fwd[b * SS + row0 + j];
        if (part == 0) srows[j] = s;
        const float* xr = x + ((size_t)(b * SS + s)) * DD + part * 48;
        #pragma unroll
        for (int i = 0; i < 12; i++) {
            float4 f = *(const float4*)(xr + i * 4);
            int col = part * 48 + i * 4;
            *(unsigned*)&lds[j][col]     = pk2(f.x, f.y);
            *(unsigned*)&lds[j][col + 2] = pk2(f.z, f.w);
        }
    }
    __syncthreads();

    // A-fragments: wave w owns rows w*16..w*16+15
    short8 a[6];
    #pragma unroll
    for (int kk = 0; kk < 6; kk++)
        a[kk] = *(const short8*)&lds[w * 16 + c][kk * 32 + g * 8];

    float mrow[4];
    #pragma unroll
    for (int r = 0; r < 4; r++)
        mrow[r] = maskf[b * SS + srows[w * 16 + g * 4 + r]];

    // emit staging buffers alias the (now dead) gather buffer
    short (*klds)[40] = (short(*)[40])&lds[0][0];
    short (*vlds)[40] = (short(*)[40])(&lds[0][0] + 64 * 40);

    #pragma unroll
    for (int hh = 0; hh < 2; hh++) {
        int h = hp * 2 + hh;
        int bh = b * HH + h;

        f32x4 aK0 = {0.f,0.f,0.f,0.f}, aK1 = {0.f,0.f,0.f,0.f};
        f32x4 aV0 = {0.f,0.f,0.f,0.f}, aV1 = {0.f,0.f,0.f,0.f};
        const short* Kp0 = WkF + (size_t)((h*2+0)*6) * 512 + lane * 8;
        const short* Kp1 = WkF + (size_t)((h*2+1)*6) * 512 + lane * 8;
        const short* Vp0 = WvF + (size_t)((h*2+0)*6) * 512 + lane * 8;
        const short* Vp1 = WvF + (size_t)((h*2+1)*6) * 512 + lane * 8;
        #pragma unroll
        for (int kk = 0; kk < 6; kk++) {
            aK0 = MFMA16(a[kk], *(const short8*)(Kp0 + kk * 512), aK0);
            aK1 = MFMA16(a[kk], *(const short8*)(Kp1 + kk * 512), aK1);
            aV0 = MFMA16(a[kk], *(const short8*)(Vp0 + kk * 512), aV0);
            aV1 = MFMA16(a[kk], *(const short8*)(Vp1 + kk * 512), aV1);
        }
        float bk0 = 0.f, bk1 = 0.f, bvv0 = 0.f, bvv1 = 0.f;
        if (2*c < 24) {
            float2 kb2 = *(const float2*)(bk + h * 24 + 2 * c);
            float2 vb2 = *(const float2*)(bv + h * 24 + 2 * c);
            bk0 = kb2.x; bk1 = kb2.y; bvv0 = vb2.x; bvv1 = vb2.y;
        }

        // guard: hh=0 -> A-frag reads done; hh=1 -> prev emit reads done
        __syncthreads();
        #pragma unroll
        for (int r = 0; r < 4; r++) {
            int row = w * 16 + g * 4 + r;
            float k0v = aK0[r] + bk0;
            float k1v = (c == 15) ? ((mrow[r] != 0.f) ? 0.f : -1e30f) : (aK1[r] + bk1);
            *(unsigned*)&klds[row][2 * c] = pk2(k0v, k1v);
            float v0v = (c == 12) ? 1.0f : (aV0[r] + bvv0);   // col 24 = ones
            float v1v = aV1[r] + bvv1;
            *(unsigned*)&vlds[row][2 * c] = pk2(v0v, v1v);
        }
        __syncthreads();
        if (t < 128) {   // K emit: 2 tiles
            int tt = (t >> 6) & 1, L = t & 63, l3 = L & 31, h2 = L >> 5;
            short* kf0 = KF + (size_t)bh * SS * DHP + (size_t)(row0 / 32 + tt) * 1024;
            #pragma unroll
            for (int i = 0; i < 2; i++) {
                short8 o = *(const short8*)&klds[tt * 32 + l3][i * 16 + h2 * 8];
                *(short8*)(kf0 + i * 512 + (size_t)L * 8) = o;
            }
        } else {         // V emit: 2 tiles, transposed
            int t2 = t - 128;
            int tt = (t2 >> 6) & 1, L = t2 & 63, l3 = L & 31, h2 = L >> 5;
            short* vf0 = VF + (size_t)bh * SS * DHP + (size_t)(row0 / 32 + tt) * 1024;
            #pragma unroll
            for (int i = 0; i < 2; i++) {
                short8 o;
                #pragma unroll
                for (int j2 = 0; j2 < 8; j2++)
                    o[j2] = vlds[tt * 32 + i * 16 + h2 * 8 + j2][l3];
                *(short8*)(vf0 + i * 512 + (size_t)L * 8) = o;
            }
        }
    }
}

// ---------------- flash attention (swapped QK^T, in-register softmax) ----------------
__device__ __forceinline__ void fproc(const f32x16& S, f32x16& acc,
                                      short8 v0, short8 v1)
{
    float p[16];
    #pragma unroll
    for (int r = 0; r < 16; r++) p[r] = __builtin_amdgcn_exp2f(S[r]);

    unsigned c01 = pk2(p[0],  p[1]);
    unsigned c23 = pk2(p[2],  p[3]);
    unsigned c45 = pk2(p[4],  p[5]);
    unsigned c67 = pk2(p[6],  p[7]);
    unsigned c89 = pk2(p[8],  p[9]);
    unsigned cab = pk2(p[10], p[11]);
    unsigned ccd = pk2(p[12], p[13]);
    unsigned cef = pk2(p[14], p[15]);

    uint2v s0 = __builtin_amdgcn_permlane32_swap(c01, c45, false, false);
    uint2v s1 = __builtin_amdgcn_permlane32_swap(c23, c67, false, false);
    uint2v s2 = __builtin_amdgcn_permlane32_swap(c89, ccd, false, false);
    uint2v s3 = __builtin_amdgcn_permlane32_swap(cab, cef, false, false);

    uint4v w0v = { s0.x, s1.x, s0.y, s1.y };   // PV A-frag, kpos tile 0..15
    uint4v w1v = { s2.x, s3.x, s2.y, s3.y };   // kpos tile 16..31
    short8 pa0 = __builtin_bit_cast(short8, w0v);
    short8 pa1 = __builtin_bit_cast(short8, w1v);

    acc = MFMA32(pa0, v0, acc);
    acc = MFMA32(pa1, v1, acc);
}

// grid 512 = 256 bh x 2 qb; 4 q-chunks per wave (ILP-4 per K/V load)
__global__ __launch_bounds__(256, 2) void flash_kernel(
    const short* __restrict__ Q, const short* __restrict__ KF, const short* __restrict__ VF,
    const int* __restrict__ cnt, short* __restrict__ Af)
{
    __shared__ float llds[4][4][32];

    int idx = blockIdx.x;
    int bh = idx & 255;
    int qb = idx >> 8;          // 0..1
    int b = bh >> 3, h = bh & 7;

    int tid = threadIdx.x;
    int lane = tid & 63, w = tid >> 6;
    int l31 = lane & 31;
    int hi = lane >> 5;

    int nt = (cnt[b] + 31) >> 5;

    int qr0 = qb * 512 + w * 32;   // chunks at qr0 + cc*128

    short8 qf[4][2];
    #pragma unroll
    for (int cc = 0; cc < 4; cc++) {
        const short* Qp = Q + ((size_t)bh * SS + qr0 + cc * 128 + l31) * DHP + hi * 8;
        qf[cc][0] = *(const short8*)Qp;
        qf[cc][1] = *(const short8*)(Qp + 16);
    }

    const short* Kp = KF + (size_t)bh * SS * DHP + (size_t)lane * 8;
    const short* Vp = VF + (size_t)bh * SS * DHP + (size_t)lane * 8;

    f32x16 acc[4], Z16;
    #pragma unroll
    for (int r = 0; r < 16; r++) {
        acc[0][r] = 0.f; acc[1][r] = 0.f; acc[2][r] = 0.f; acc[3][r] = 0.f;
        Z16[r] = 0.f;
    }

    short8 k0 = *(const short8*)(Kp);
    short8 k1 = *(const short8*)(Kp + 512);
    short8 v0 = *(const short8*)(Vp);
    short8 v1 = *(const short8*)(Vp + 512);

    for (int kt = 0; kt < nt; kt++) {
        Kp += 1024;
        Vp += 1024;
        short8 nk0 = *(const short8*)(Kp);
        short8 nk1 = *(const short8*)(Kp + 512);
        short8 nv0 = *(const short8*)(Vp);
        short8 nv1 = *(const short8*)(Vp + 512);

        #pragma unroll
        for (int cc = 0; cc < 4; cc++) {
            f32x16 S = MFMA32(k0, qf[cc][0], Z16);
            S = MFMA32(k1, qf[cc][1], S);   // includes mask bias via channel e=31
            fproc(S, acc[cc], v0, v1);
        }

        k0 = nk0; k1 = nk1; v0 = nv0; v1 = nv1;
    }

    if (l31 == 24) {
        #pragma unroll
        for (int cc = 0; cc < 4; cc++) {
            #pragma unroll
            for (int r = 0; r < 16; r++) {
                int row = (r & 3) + 8 * (r >> 2) + 4 * hi;
                llds[w][cc][row] = __builtin_amdgcn_rcpf(acc[cc][r]);
            }
        }
    }
    __builtin_amdgcn_wave_barrier();

    if (l31 < 24) {
        int d = h * 24 + l31;
        size_t fcol = (size_t)((d >> 5) * 4 + ((d >> 3) & 3)) * 128 + (d & 7);
        #pragma unroll
        for (int cc = 0; cc < 4; cc++) {
            int grp = (b * SS + qr0 + cc * 128) >> 4;
            short* op = Af + (size_t)grp * 3072 + fcol;   // 3072 = 24*128
            #pragma unroll
            for (int r = 0; r < 16; r++) {
                int row = (r & 3) + 8 * (r >> 2) + 4 * hi;
                size_t off = (size_t)(r >> 3) * 3072 + (size_t)(row & 15) * 8;
                op[off] = nb(acc[cc][r] * llds[w][cc][row]);
            }
        }
    }
}

// ---------------- final: out = attn(bf16) @ Wo(bf16) + bo ----------------
__global__ __launch_bounds__(256) void final_kernel(
    const short* __restrict__ Af,
    const short* __restrict__ WoFh,
    const float* __restrict__ bo, float* __restrict__ out)
{
    int tid = threadIdx.x;
    int lane = tid & 63, w = tid >> 6;
    int c = lane & 15, g = lane >> 4;
    int r0 = blockIdx.x * 64 + w * 16;
    int n0 = blockIdx.y * 3;

    short8 a[6];
    #pragma unroll
    for (int kk = 0; kk < 6; kk++)
        a[kk] = *(const short8*)(Af + ((size_t)(r0 >> 4) * 24 + kk*4 + g) * 128 + c * 8);

    f32x4 acc[3];
    #pragma unroll
    for (int n = 0; n < 3; n++) acc[n] = (f32x4){0.f,0.f,0.f,0.f};

    #pragma unroll
    for (int kk = 0; kk < 6; kk++) {
        #pragma unroll
        for (int n = 0; n < 3; n++) {
            short8 bh = *(const short8*)(WoFh + (size_t)((n0+n)*6 + kk) * 512 + lane * 8);
            acc[n] = MFMA16(a[kk], bh, acc[n]);
        }
    }

    #pragma unroll
    for (int n = 0; n < 3; n++) {
        int col = (n0+n)*16 + c;
        float bv = bo[col];
        #pragma unroll
        for (int r = 0; r < 4; r++) {
            out[(size_t)(r0 + g*4 + r) * DD + col] = acc[n][r] + bv;
        }
    }
}

extern "C" void kernel_launch(void* const* d_in, const int* in_sizes, int n_in,
                              void* d_out, int out_size, void* d_ws, size_t ws_size,
                              hipStream_t stream)
{
    const float* x    = (const float*)d_in[0];
    const void*  mask = d_in[1];
    const float* Wq   = (const float*)d_in[2];
    const float* bq   = (const float*)d_in[3];
    const float* Wk   = (const float*)d_in[4];
    const float* bk   = (const float*)d_in[5];
    const float* Wv   = (const float*)d_in[6];
    const float* bv   = (const float*)d_in[7];
    const float* Wo   = (const float*)d_in[8];
    const float* bo   = (const float*)d_in[9];
    float* out = (float*)d_out;

    char* ws = (char*)d_ws;
    size_t off = 0;
    float* maskf = (float*)(ws + off); off += (size_t)BB*SS*4;          // 128 KB
    short* Q     = (short*)(ws + off); off += (size_t)BB*HH*SS*DHP*2;   // 16 MB
    short* KF    = (short*)(ws + off); off += (size_t)BB*HH*SS*DHP*2;   // 16 MB
    short* VF    = (short*)(ws + off); off += (size_t)BB*HH*SS*DHP*2;   // 16 MB
    short* Af    = (short*)(ws + off); off += (size_t)BB*SS*DD*2;       // 12 MB
    short* xF    = (short*)(ws + off); off += (size_t)BB*SS*DD*2;       // 12.6 MB
    short* WqF   = (short*)(ws + off); off += (size_t)HH*DHP*DD*2;
    short* WkF   = (short*)(ws + off); off += (size_t)HH*DHP*DD*2;
    short* WvF   = (short*)(ws + off); off += (size_t)HH*DHP*DD*2;
    short* WoFh  = (short*)(ws + off); off += (size_t)DD*DD*2;
    int*   fwd   = (int*)  (ws + off); off += (size_t)BB*SS*4;          // 128 KB
    int*   cnt   = (int*)  (ws + off); off += 256;

    setup_kernel<<<dim3(NBLK_PREP + NBLK_XPREP + BB), dim3(256), 0, stream>>>(
        Wq, Wk, Wv, Wo, x, mask, WqF, WkF, WvF, WoFh, xF, maskf, fwd, cnt);
    proj2_kernel<<<dim3(4096), dim3(256), 0, stream>>>(
        x, xF, bq, bk, bv, WqF, WkF, WvF, maskf, fwd, cnt, Q, KF, VF);
    flash_kernel<<<dim3(512), dim3(256), 0, stream>>>(
        Q, KF, VF, cnt, Af);
    final_kernel<<<dim3(512, 4), dim3(256), 0, stream>>>(
        Af, WoFh, bo, out);
}